// Round 2
// 352.044 us; speedup vs baseline: 3.1636x; 3.1636x over previous
//
#include <hip/hip_runtime.h>

#define H 320
#define W 320
#define HW (H * W)          // 102400
#define CH 64

typedef _Float16 f16;
typedef _Float16 f16x8 __attribute__((ext_vector_type(8)));
typedef float f32x16 __attribute__((ext_vector_type(16)));

// ---------------- bicubic x2 upsample (query 3x160x160 -> 3x320x320) --------
__device__ __forceinline__ float cubw(float t) {
    t = fabsf(t);
    if (t <= 1.f) return (1.25f * t - 2.25f) * t * t + 1.f;        // A=-0.75
    if (t < 2.f)  return -0.75f * (((t - 5.f) * t + 8.f) * t - 4.f);
    return 0.f;
}

__global__ __launch_bounds__(256) void bicubic_k(const float* __restrict__ q,
                                                 float* __restrict__ outp) {
    int idx = blockIdx.x * 256 + threadIdx.x;
    if (idx >= 3 * HW) return;
    int c = idx / HW;
    int r = idx - c * HW;
    int oy = r / W, ox = r - (r / W) * W;
    float sy = oy * 0.5f - 0.25f;
    float sx = ox * 0.5f - 0.25f;
    int iy0 = (int)floorf(sy);
    int ix0 = (int)floorf(sx);
    float wy[4], wx[4];
    int tyi[4], txi[4];
#pragma unroll
    for (int a = 0; a < 4; a++) {
        int ty = iy0 - 1 + a;
        wy[a] = cubw(sy - (float)ty);
        tyi[a] = min(max(ty, 0), 159);
        int tx = ix0 - 1 + a;
        wx[a] = cubw(sx - (float)tx);
        txi[a] = min(max(tx, 0), 159);
    }
    const float* ip = q + c * (160 * 160);
    float o = 0.f;
#pragma unroll
    for (int b = 0; b < 4; b++) {
        float s = 0.f;
#pragma unroll
        for (int a = 0; a < 4; a++) s += wy[a] * ip[tyi[a] * 160 + txi[b]];
        o += wx[b] * s;
    }
    outp[idx] = o;
}

// ---------------- direct 5x5 conv, CIN=3 (head conv1), out = NHWC f16 -------
// CIN=3 is MFMA-hostile (K=3/tap); keep the tuned direct kernel, emit NHWC f16.
__global__ __launch_bounds__(256, 3) void hconv_k(const float* __restrict__ in,
                                                  const float* __restrict__ wgt,
                                                  const float* __restrict__ bias,
                                                  f16* __restrict__ out) {
    constexpr int KS = 5, PAD = 2;
    constexpr int TWX = 36, TWY = 36, TSTR = 37;   // odd stride: bank-parity trick
    constexpr int KS2 = 25, WSTR = 28;
    constexpr int ICB = 3, OCB = 4;

    __shared__ float tile[ICB][TWY][TSTR];
    __shared__ float wl[ICB][OCB][WSTR];

    const int tid = threadIdx.x;
    const int tx = tid & 15, ty = tid >> 4;
    const int tileId = blockIdx.x >> 3;
    const int oc0 = (blockIdx.x & 7) * OCB;
    const int x0 = (tileId % 10) * 32;
    const int y0 = (tileId / 10) * 32;

    float acc[OCB][4];
#pragma unroll
    for (int i = 0; i < OCB; i++)
#pragma unroll
        for (int j = 0; j < 4; j++) acc[i][j] = 0.f;

    // stage input tile (+halo)
    for (int idx = tid; idx < ICB * TWY * TWX; idx += 256) {
        int icc = idx / (TWY * TWX);
        int rem = idx - icc * (TWY * TWX);
        int r = rem / TWX, c = rem - r * TWX;
        int iy = y0 - PAD + r;
        int ix = x0 - PAD + c;
        float v = 0.f;
        if (iy >= 0 && iy < H && ix >= 0 && ix < W)
            v = in[icc * HW + iy * W + ix];
        tile[icc][r][c] = v;
    }
    for (int idx = tid; idx < ICB * OCB * KS2; idx += 256) {
        int icc = idx / (OCB * KS2);
        int rem = idx - icc * (OCB * KS2);
        int oc = rem / KS2, t = rem - oc * KS2;
        wl[icc][oc][t] = wgt[((oc0 + oc) * ICB + icc) * KS2 + t];
    }
    __syncthreads();

#pragma unroll
    for (int icc = 0; icc < ICB; ++icc) {
        float win[2][KS][KS + 1];
#pragma unroll
        for (int h = 0; h < 2; h++)
#pragma unroll
            for (int r = 0; r < KS; r++)
#pragma unroll
                for (int c = 0; c < KS + 1; c++)
                    win[h][r][c] = tile[icc][ty + 16 * h + r][2 * tx + c];
#pragma unroll
        for (int oc = 0; oc < OCB; ++oc) {
            float wv[KS2];
#pragma unroll
            for (int t = 0; t < KS2; t++) wv[t] = wl[icc][oc][t];
#pragma unroll
            for (int h = 0; h < 2; h++)
#pragma unroll
                for (int r = 0; r < KS; r++)
#pragma unroll
                    for (int c = 0; c < KS; c++) {
                        acc[oc][2 * h]     += win[h][r][c]     * wv[r * KS + c];
                        acc[oc][2 * h + 1] += win[h][r][c + 1] * wv[r * KS + c];
                    }
        }
    }

    const int col = x0 + 2 * tx;
#pragma unroll
    for (int oc = 0; oc < OCB; ++oc) {
        float bv = bias[oc0 + oc];
#pragma unroll
        for (int h = 0; h < 2; h++) {
            int row = y0 + ty + 16 * h;
            int pix = row * W + col;
#pragma unroll
            for (int c2 = 0; c2 < 2; c2++) {
                float v = acc[oc][2 * h + c2] + bv;
                v = (v > 0.f) ? v : 0.2f * v;          // lrelu
                out[(pix + c2) * 32 + oc0 + oc] = (f16)v;
            }
        }
    }
}

// ---------------- weight repack: OIHW fp32 -> MFMA B-fragment order f16 -----
// Per layer, per (kc, tap), lane l holds B[k=8*(l>>5)+i][oc=l&31] as one f16x8.
// Layout: dst[base + ((kc*KS2 + t)*64 + l)*8 + i].
__global__ __launch_bounds__(256) void repack_k(const float* __restrict__ w0, // r1_w1
                                                const float* __restrict__ w1, // r1_w2
                                                const float* __restrict__ w2, // pr_w1
                                                const float* __restrict__ w3, // pr_w2
                                                const float* __restrict__ w4, // p1_w
                                                f16* __restrict__ dst) {
    int li = blockIdx.x * 256 + threadIdx.x;
    const float* src;
    int CIN, KS2, base, rel;
    if (li < 1152)       { src = w0; CIN = 32; KS2 = 9;  base = 0;     rel = li; }
    else if (li < 2304)  { src = w1; CIN = 32; KS2 = 9;  base = 9216;  rel = li - 1152; }
    else if (li < 3456)  { src = w2; CIN = 32; KS2 = 9;  base = 18432; rel = li - 2304; }
    else if (li < 4608)  { src = w3; CIN = 32; KS2 = 9;  base = 27648; rel = li - 3456; }
    else if (li < 11008) { src = w4; CIN = 64; KS2 = 25; base = 36864; rel = li - 4608; }
    else return;
    int fi = rel >> 6, l = rel & 63;
    int kc = fi / KS2, t = fi - kc * KS2;
    int oc = l & 31, kh = l >> 5;
#pragma unroll
    for (int i = 0; i < 8; ++i) {
        int ic = kc * 16 + kh * 8 + i;
        dst[base + rel * 8 + i] = (f16)src[(oc * CIN + ic) * KS2 + t];
    }
}

// ---------------- MFMA implicit-GEMM conv (NHWC f16 in/out, fp32 accum) -----
// Tap-decomposed GEMM on v_mfma_f32_32x32x16_f16:
//   D[pixel 0..31][oc 0..31] += A[pixel][k=ic16] * B[k][oc], per tap, per kc.
// Tile: 8 rows x 32 cols per block (400 blocks), wave w owns rows 2w,2w+1.
// A from LDS (NHWC tile + halo, staged once). LDS held as 8B units with
// XOR swizzle u^(p&(NU-1)): 64/128B pixel rows otherwise alias banks.
// Layouts (gfx950): D col=lane&31, row=(reg&3)+8*(reg>>2)+4*(lane>>5);
// A row=lane&31, k=8*(lane>>5)+i; B col=lane&31, k=8*(lane>>5)+i (repacked).
template <int KS, int CIN, int ACT, bool RES>
__global__ __launch_bounds__(256) void mconv_k(const f16* __restrict__ in,
                                               const f16* __restrict__ wrep,
                                               const float* __restrict__ bias,
                                               const f16* __restrict__ res,
                                               f16* __restrict__ out,
                                               int OUTC, int oc0) {
    constexpr int PAD = KS / 2;
    constexpr int TY = 8 + 2 * PAD;
    constexpr int TX = 32 + 2 * PAD;
    constexpr int NPX = TY * TX;
    constexpr int NU = CIN / 4;           // 8B units per pixel
    constexpr int UM = NU - 1;
    constexpr int KC = CIN / 16;
    constexpr int KS2 = KS * KS;

    __shared__ uint2 lds2[NPX * NU];      // 55.3 KB (CIN=64) / 21.8 KB (CIN=32)

    const int tid = threadIdx.x;
    const int bx = blockIdx.x % 10;
    const int by = blockIdx.x / 10;
    const int x0 = bx * 32, y0 = by * 8;

    // ---- stage NHWC tile (+halo), coalesced 8B loads, swizzled ds_writes ---
    {
        const int cu = tid & UM;
        constexpr int STEP = 256 / NU;    // 16 (CIN=64) or 32 (CIN=32)
        for (int p = tid / NU; p < NPX; p += STEP) {
            int ly = p / TX, lx = p - ly * TX;
            int gy = y0 - PAD + ly, gx = x0 - PAD + lx;
            uint2 v; v.x = 0u; v.y = 0u;
            if (gy >= 0 && gy < H && gx >= 0 && gx < W)
                v = *reinterpret_cast<const uint2*>(in + (gy * W + gx) * CIN + cu * 4);
            lds2[p * NU + (cu ^ (p & UM))] = v;
        }
    }
    __syncthreads();

    const int lane = tid & 63;
    const int wv = tid >> 6;              // wave 0..3
    const int R = lane & 31;              // A pixel-x / B,D oc column
    const int hh = lane >> 5;

    f32x16 acc0, acc1;
#pragma unroll
    for (int j = 0; j < 16; ++j) { acc0[j] = 0.f; acc1[j] = 0.f; }

#pragma unroll
    for (int kc = 0; kc < KC; ++kc) {
#pragma unroll
        for (int t = 0; t < KS2; ++t) {
            const int dy = t / KS, dx = t - dy * KS;
            f16x8 B = *reinterpret_cast<const f16x8*>(
                wrep + ((kc * KS2 + t) * 64 + lane) * 8);
            const int u0 = (kc * 2 + hh) * 2;
            {   // m = 0
                int p = (2 * wv + 0 + dy) * TX + R + dx;
                union { uint2 u[2]; f16x8 v; } A;
                A.u[0] = lds2[p * NU + ((u0)     ^ (p & UM))];
                A.u[1] = lds2[p * NU + ((u0 + 1) ^ (p & UM))];
                acc0 = __builtin_amdgcn_mfma_f32_32x32x16_f16(A.v, B, acc0, 0, 0, 0);
            }
            {   // m = 1
                int p = (2 * wv + 1 + dy) * TX + R + dx;
                union { uint2 u[2]; f16x8 v; } A;
                A.u[0] = lds2[p * NU + ((u0)     ^ (p & UM))];
                A.u[1] = lds2[p * NU + ((u0 + 1) ^ (p & UM))];
                acc1 = __builtin_amdgcn_mfma_f32_32x32x16_f16(A.v, B, acc1, 0, 0, 0);
            }
        }
    }

    // ---- epilogue: bias (+res) + activation, NHWC f16 stores ---------------
    const float bv = bias[R];
#pragma unroll
    for (int m = 0; m < 2; ++m) {
        const int gy = y0 + 2 * wv + m;
        f32x16 a = m ? acc1 : acc0;
#pragma unroll
        for (int r = 0; r < 16; ++r) {
            int X = x0 + (r & 3) + 8 * (r >> 2) + 4 * hh;
            int pix = gy * W + X;
            float v = a[r] + bv;
            if constexpr (RES) v += (float)res[pix * 32 + R];
            if constexpr (ACT == 0) v = fmaxf(v, 0.f);
            else                    v = (v > 0.f) ? v : 0.2f * v;
            out[pix * OUTC + oc0 + R] = (f16)v;
        }
    }
}

// ---------------- 1x1 conv 32->3 (NHWC f16 in), +1, clip --------------------
__global__ __launch_bounds__(256) void affine_k(const f16* __restrict__ hid,
                                                const float* __restrict__ w,
                                                const float* __restrict__ b,
                                                float* __restrict__ outp) {
    int p = blockIdx.x * 256 + threadIdx.x;
    if (p >= HW) return;
    const f16x8* hv = reinterpret_cast<const f16x8*>(hid + p * 32);
    float a0 = 0.f, a1 = 0.f, a2 = 0.f;
#pragma unroll
    for (int cc = 0; cc < 4; ++cc) {
        f16x8 hb = hv[cc];
#pragma unroll
        for (int j = 0; j < 8; ++j) {
            float hval = (float)hb[j];
            int c = cc * 8 + j;
            a0 += hval * w[c];
            a1 += hval * w[32 + c];
            a2 += hval * w[64 + c];
        }
    }
    a0 = fminf(fmaxf(a0 + b[0] + 1.f, -3.f), 3.f);
    a1 = fminf(fmaxf(a1 + b[1] + 1.f, -3.f), 3.f);
    a2 = fminf(fmaxf(a2 + b[2] + 1.f, -3.f), 3.f);
    outp[p] = a0;
    outp[HW + p] = a1;
    outp[2 * HW + p] = a2;
}

// ---------------- deformable 2x2 bilinear sampling --------------------------
__device__ __forceinline__ int reflmap(int q) {
    int s = q - 1;
    if (s < 0) s = -s;
    else if (s > 319) s = 638 - s;
    return s;
}

__global__ __launch_bounds__(256) void sample_k(const float* __restrict__ x,
                                                const float* __restrict__ aff,
                                                float* __restrict__ outp) {
    int idx = blockIdx.x * 256 + threadIdx.x;   // over 640*640 output pixels
    if (idx >= 640 * 640) return;
    int ow = idx % 640, oh = idx / 640;
    int w = ow >> 1, h = oh >> 1;
    int ky = ow & 1, kx = oh & 1;
    int p = h * W + w;
    float s_x = aff[p];
    float s_y = aff[HW + p];
    float th = (aff[2 * HW + p] - 1.f) * 1.0472f;
    float pnx = kx ? 0.5f : -0.5f;
    float pny = ky ? 0.5f : -0.5f;
    float px = pnx * s_x, py = pny * s_y;
    float st, ct;
    __sincosf(th, &st, &ct);
    float rx = px * ct - py * st;
    float ry = px * st + py * ct;
    float p_x = rx + 0.5f + (float)(h + 1);
    float p_y = ry + 0.5f + (float)(w + 1);
    float ltx = floorf(p_x), lty = floorf(p_y);
    float rbx = ltx + 1.f, rby = lty + 1.f;
    float ltxc = fminf(fmaxf(ltx, 0.f), 321.f);
    float ltyc = fminf(fmaxf(lty, 0.f), 321.f);
    float rbxc = fminf(fmaxf(rbx, 0.f), 321.f);
    float rbyc = fminf(fmaxf(rby, 0.f), 321.f);
    p_x = fminf(fmaxf(p_x, 0.f), 321.f);
    p_y = fminf(fmaxf(p_y, 0.f), 321.f);
    float gx0 = 1.f + ltxc - p_x;
    float gx1 = 1.f - (rbxc - p_x);
    float gy0 = 1.f + ltyc - p_y;
    float gy1 = 1.f - (rbyc - p_y);
    float g_lt = gx0 * gy0, g_rb = gx1 * gy1, g_lb = gx0 * gy1, g_rt = gx1 * gy0;
    int ix0 = reflmap((int)ltxc), ix1 = reflmap((int)rbxc);
    int iy0 = reflmap((int)ltyc), iy1 = reflmap((int)rbyc);
    int o00 = ix0 * W + iy0;
    int o11 = ix1 * W + iy1;
    int o01 = ix0 * W + iy1;
    int o10 = ix1 * W + iy0;
    int obase = oh * 640 + ow;
    for (int c = 0; c < CH; c++) {
        const float* xc = x + c * HW;
        float v = g_lt * xc[o00] + g_rb * xc[o11] + g_lb * xc[o01] + g_rt * xc[o10];
        outp[c * (640 * 640) + obase] = v;
    }
}

// ---------------- launch ----------------------------------------------------
extern "C" void kernel_launch(void* const* d_in, const int* in_sizes, int n_in,
                              void* d_out, int out_size, void* d_ws, size_t ws_size,
                              hipStream_t stream) {
    const float* x       = (const float*)d_in[0];
    const float* query   = (const float*)d_in[1];
    const float* ref     = (const float*)d_in[2];
    const float* conv1_w = (const float*)d_in[3];
    const float* conv1_b = (const float*)d_in[4];
    const float* r1_w1   = (const float*)d_in[5];
    const float* r1_b1   = (const float*)d_in[6];
    const float* r1_w2   = (const float*)d_in[7];
    const float* r1_b2   = (const float*)d_in[8];
    const float* p1_w    = (const float*)d_in[9];
    const float* p1_b    = (const float*)d_in[10];
    const float* pr_w1   = (const float*)d_in[11];
    const float* pr_b1   = (const float*)d_in[12];
    const float* pr_w2   = (const float*)d_in[13];
    const float* pr_b2   = (const float*)d_in[14];
    const float* p2_w    = (const float*)d_in[15];
    const float* p2_b    = (const float*)d_in[16];

    float* outp = (float*)d_out;
    float* ws = (float*)d_ws;

    // ws (2.4 MB): fp32 qup + affine. d_out (104.8 MB) holds NHWC-f16
    // intermediates + repacked weights; all dead before sample_k rewrites it.
    float* qup    = ws;                       // 3*HW fp32
    float* affine = ws + 3 * HW;              // 3*HW fp32
    f16* feat = (f16*)outp;                   // [HW][64]  (rf ch 0..31, qf 32..63)
    f16* Bt   = (f16*)(outp + 32 * HW);       // [HW][32]
    f16* Ct   = (f16*)(outp + 48 * HW);       // [HW][32]
    f16* Dt   = (f16*)(outp + 64 * HW);       // [HW][32]
    f16* wrep = (f16*)(outp + 80 * HW);       // 88064 f16 repacked weights

    repack_k<<<43, 256, 0, stream>>>(r1_w1, r1_w2, pr_w1, pr_w2, p1_w, wrep);
    bicubic_k<<<1200, 256, 0, stream>>>(query, qup);

    // qf head
    hconv_k<<<800, 256, 0, stream>>>(qup, conv1_w, conv1_b, Bt);
    mconv_k<3, 32, 0, false><<<400, 256, 0, stream>>>(Bt, wrep,         r1_b1, nullptr, Ct, 32, 0);
    mconv_k<3, 32, 1, true ><<<400, 256, 0, stream>>>(Ct, wrep + 9216,  r1_b2, Bt, feat, 64, 32);

    // rf head
    hconv_k<<<800, 256, 0, stream>>>(ref, conv1_w, conv1_b, Bt);
    mconv_k<3, 32, 0, false><<<400, 256, 0, stream>>>(Bt, wrep,         r1_b1, nullptr, Ct, 32, 0);
    mconv_k<3, 32, 1, true ><<<400, 256, 0, stream>>>(Ct, wrep + 9216,  r1_b2, Bt, feat, 64, 0);

    // fusion head
    mconv_k<5, 64, 1, false><<<400, 256, 0, stream>>>(feat, wrep + 36864, p1_b, nullptr, Bt, 32, 0);
    mconv_k<3, 32, 0, false><<<400, 256, 0, stream>>>(Bt, wrep + 18432, pr_b1, nullptr, Ct, 32, 0);
    mconv_k<3, 32, 1, true ><<<400, 256, 0, stream>>>(Ct, wrep + 27648, pr_b2, Bt, Dt, 32, 0);

    affine_k<<<400, 256, 0, stream>>>(Dt, p2_w, p2_b, affine);

    sample_k<<<1600, 256, 0, stream>>>(x, affine, outp);
}